// Round 2
// baseline (245.319 us; speedup 1.0000x reference)
//
#include <hip/hip_runtime.h>

// SegmentLUT, float-approximation path.
// Reference (int): xi = clip(rint(x/s)); idx = searchsorted_left(segment_max, xi);
//   acc = k[idx]*xi + (b[idx]<<ls[idx]); qy = clip((acc + rbias) >> rs[idx]); y = qy*os.
// Float path: y = clamp(fmaf(kf[idx], xi_f, bf[idx]), -32768*os, 32767*os)
//   where kf = k * 2^-rs * os, bf = ((b<<ls)+rbias) * 2^-rs * os.
// Max deviation from the integer reference: ~1 quant unit (floor/round diff)
//   + fp32 rounding of a <=2^28 accumulator >> rs>=1  => ~0.01 absolute,
//   vs harness threshold 0.655.  (div -> mul-by-recip is bit-exact here: s = 2^-13.)

__device__ __forceinline__ float seg_one(float x, float inv_s,
                                         float sm0, float sm1, float sm2, float sm3,
                                         float sm4, float sm5, float sm6,
                                         const float2* tab, float olo, float ohi)
{
    float xf = rintf(x * inv_s);                    // round half-even, matches np.round
    xf = fminf(fmaxf(xf, -32768.0f), 32767.0f);     // clamp BEFORE compares (idx semantics)
    int idx = (sm0 < xf) + (sm1 < xf) + (sm2 < xf) + (sm3 < xf)
            + (sm4 < xf) + (sm5 < xf) + (sm6 < xf); // searchsorted left, idx in [0,7]
    float2 t = tab[idx];                            // ds_read_b64, conflict-free
    float y = fmaf(t.x, xf, t.y);                   // (k*xi + b') * 2^-rs * os, fused
    return fminf(fmaxf(y, olo), ohi);               // clip(qy) * os
}

__global__ __launch_bounds__(256) void SegmentLUT_83021717831949_kernel(
    const float* __restrict__ x,
    const float* __restrict__ input_scale,
    const float* __restrict__ out_scale,
    const int*   __restrict__ alpha,
    const int*   __restrict__ beta,
    const int*   __restrict__ lsh,
    const int*   __restrict__ rsh,
    const int*   __restrict__ smax,
    float*       __restrict__ out,
    int n)
{
    __shared__ float2 tab[8];   // {kf, bf} per segment
    float os = out_scale[0];
    if (threadIdx.x < 8) {
        int j  = (int)threadIdx.x;
        int rs = rsh[j];
        int rm1 = rs - 1 > 0 ? rs - 1 : 0;
        int rbias = rs > 0 ? (1 << rm1) : 0;
        int bc = (int)((unsigned)beta[j] << (lsh[j] & 31)) + rbias;  // int32 wrap like ref
        float sc = ldexpf(os, -rs);                                   // os * 2^-rs
        tab[j] = make_float2((float)alpha[j] * sc, (float)bc * sc);
    }
    float s     = input_scale[0];
    float inv_s = 1.0f / s;                    // hoisted; exact for power-of-two s
    float sm0 = (float)smax[0], sm1 = (float)smax[1], sm2 = (float)smax[2];
    float sm3 = (float)smax[3], sm4 = (float)smax[4], sm5 = (float)smax[5];
    float sm6 = (float)smax[6];
    float olo = -32768.0f * os, ohi = 32767.0f * os;
    __syncthreads();

    int nvec   = n >> 2;
    int stride = (int)(gridDim.x * blockDim.x);
    int tid    = (int)(blockIdx.x * blockDim.x + threadIdx.x);

    const float4* __restrict__ xv = (const float4*)x;
    float4* __restrict__ ov = (float4*)out;

    int i = tid;
    // 2-way unroll: two independent float4 loads in flight per iteration.
    for (; i + stride < nvec; i += 2 * stride) {
        float4 a = xv[i];
        float4 b = xv[i + stride];
        float4 oa, ob;
        oa.x = seg_one(a.x, inv_s, sm0, sm1, sm2, sm3, sm4, sm5, sm6, tab, olo, ohi);
        oa.y = seg_one(a.y, inv_s, sm0, sm1, sm2, sm3, sm4, sm5, sm6, tab, olo, ohi);
        oa.z = seg_one(a.z, inv_s, sm0, sm1, sm2, sm3, sm4, sm5, sm6, tab, olo, ohi);
        oa.w = seg_one(a.w, inv_s, sm0, sm1, sm2, sm3, sm4, sm5, sm6, tab, olo, ohi);
        ob.x = seg_one(b.x, inv_s, sm0, sm1, sm2, sm3, sm4, sm5, sm6, tab, olo, ohi);
        ob.y = seg_one(b.y, inv_s, sm0, sm1, sm2, sm3, sm4, sm5, sm6, tab, olo, ohi);
        ob.z = seg_one(b.z, inv_s, sm0, sm1, sm2, sm3, sm4, sm5, sm6, tab, olo, ohi);
        ob.w = seg_one(b.w, inv_s, sm0, sm1, sm2, sm3, sm4, sm5, sm6, tab, olo, ohi);
        ov[i] = oa;
        ov[i + stride] = ob;
    }
    for (; i < nvec; i += stride) {        // runs at most once after the 2-way loop
        float4 a = xv[i];
        float4 oa;
        oa.x = seg_one(a.x, inv_s, sm0, sm1, sm2, sm3, sm4, sm5, sm6, tab, olo, ohi);
        oa.y = seg_one(a.y, inv_s, sm0, sm1, sm2, sm3, sm4, sm5, sm6, tab, olo, ohi);
        oa.z = seg_one(a.z, inv_s, sm0, sm1, sm2, sm3, sm4, sm5, sm6, tab, olo, ohi);
        oa.w = seg_one(a.w, inv_s, sm0, sm1, sm2, sm3, sm4, sm5, sm6, tab, olo, ohi);
        ov[i] = oa;
    }
    // Scalar tail for n % 4 != 0 (not hit for this shape).
    for (int k = (nvec << 2) + tid; k < n; k += stride) {
        out[k] = seg_one(x[k], inv_s, sm0, sm1, sm2, sm3, sm4, sm5, sm6, tab, olo, ohi);
    }
}

extern "C" void kernel_launch(void* const* d_in, const int* in_sizes, int n_in,
                              void* d_out, int out_size, void* d_ws, size_t ws_size,
                              hipStream_t stream) {
    const float* x           = (const float*)d_in[0];
    const float* input_scale = (const float*)d_in[1];
    const float* out_scale   = (const float*)d_in[2];
    const int*   alpha       = (const int*)d_in[3];
    const int*   beta        = (const int*)d_in[4];
    const int*   lsh         = (const int*)d_in[5];
    const int*   rsh         = (const int*)d_in[6];
    const int*   smax        = (const int*)d_in[7];
    float* out = (float*)d_out;

    int n = in_sizes[0];
    int nvec = n >> 2;
    int blocks = (nvec + 255) / 256;
    if (blocks > 2048) blocks = 2048;
    if (blocks < 1) blocks = 1;

    SegmentLUT_83021717831949_kernel<<<blocks, 256, 0, stream>>>(
        x, input_scale, out_scale, alpha, beta, lsh, rsh, smax, out, n);
}